// Round 6
// baseline (321.555 us; speedup 1.0000x reference)
//
#include <hip/hip_runtime.h>
#include <hip/hip_fp16.h>

#define N_NODES 10000
#define E_EDGES 320000
#define F_IN    256
#define F_PROJ  200

typedef float vfloat4 __attribute__((ext_vector_type(4)));

// ---------------- ev region geometry (new path) ------------------------------
#define REG_FLOATS 20000            // exactly 2 rows of ev per region
#define REG_F4     5000
#define NREGIONS   5000             // 5000 * 20000 = 1e8 floats = ev
#define CAP        384              // bucket capacity; mean 128, +13 sigma

#define K1_PROJ_BLOCKS 1250
#define K1_COPY_REGS   300          // regions [0,300) copied in K1
#define K2_ALPHA_BLOCKS 1536
#define K2_ALPHA_WAVES  (K2_ALPHA_BLOCKS * 4)
#define ALPHA_CHUNK ((E_EDGES + K2_ALPHA_WAVES - 1) / K2_ALPHA_WAVES)  // 53
#define K2_COPY_REG0   300
#define K2_COPY_REGS   600          // regions [300,900) copied in K2
#define K2_AGG_BLOCKS  160
#define AGG_N4         (N_NODES * F_IN / 4)          // 640000
#define AGG_PER_BLOCK  (AGG_N4 / K2_AGG_BLOCKS)      // 4000
#define K3_COPY_REG0   900
#define K3_COPY_REGS   (NREGIONS - K3_COPY_REG0)     // 4100

// new-path workspace layout
#define WS_P       0L
#define WS_FLAGS   4000000L
#define WS_SUM     4040000L
#define WS_COUNTS  4040016L
#define WS_BUCKET  4060016L
#define WS_NEED    (WS_BUCKET + (long)NREGIONS * CAP * 4)   // 11,740,016

__device__ __forceinline__ unsigned short f32_to_bf16(float f) {
    unsigned int u = __float_as_uint(f);
    u += 0x7FFFu + ((u >> 16) & 1u);
    return (unsigned short)(u >> 16);
}
__device__ __forceinline__ float bf16_to_f32(unsigned short b) {
    return __uint_as_float(((unsigned int)b) << 16);
}

// ================= NEW PATH ==================================================

// ---- K1: proj + flags (1250 blocks)  ||  nt-copy regions [0,300) ------------
__global__ __launch_bounds__(256) void k1_proj_flags_copy(
        const float* __restrict__ x,
        const float* __restrict__ W,
        unsigned short* __restrict__ P,
        const int* __restrict__ ei,
        int* __restrict__ flags,
        const vfloat4* __restrict__ csrc,
        vfloat4* __restrict__ cdst) {
    int bid = blockIdx.x, tid = threadIdx.x;
    if (bid >= K1_PROJ_BLOCKS) {
        long r = bid - K1_PROJ_BLOCKS;             // region 0..299
        const vfloat4* s = csrc + r * REG_F4;
        vfloat4*       d = cdst + r * REG_F4;
        for (int i = tid; i < REG_F4; i += 256) {
            vfloat4 v = __builtin_nontemporal_load(s + i);
            __builtin_nontemporal_store(v, d + i);
        }
        return;
    }
    // flags: 1250*256 = 320000 threads == E
    int gt = bid * 256 + tid;
    flags[ei[E_EDGES + gt]] = 1;                   // racy same-value store: fine

    __shared__ float xs[8][F_IN];
    int n0 = bid * 8;
    for (int i = tid; i < 8 * F_IN / 4; i += 256)
        ((float4*)xs)[i] = ((const float4*)(x + (long)n0 * F_IN))[i];
    __syncthreads();
    int j = tid;
    if (j >= F_PROJ) return;
    float acc[8] = {0.f,0.f,0.f,0.f,0.f,0.f,0.f,0.f};
    for (int k = 0; k < F_IN; ++k) {
        float w = W[k * F_PROJ + j];
        #pragma unroll
        for (int r = 0; r < 8; ++r) acc[r] += xs[r][k] * w;
    }
    #pragma unroll
    for (int r = 0; r < 8; ++r) P[(long)(n0 + r) * F_PROJ + j] = f32_to_bf16(acc[r]);
}

// ---- K2: alpha + bucket-insert (1536) || nt-copy [300,900) || agg (160) -----
__global__ __launch_bounds__(256) void k2_alpha_copy_agg(
        const int* __restrict__ ei,
        const unsigned short* __restrict__ P,
        const float* __restrict__ Watt,
        const float* __restrict__ batt,
        float* __restrict__ sumbuf,               // pre-zeroed
        unsigned int* __restrict__ counts,        // pre-zeroed [NREGIONS]
        unsigned int* __restrict__ bucket,        // [NREGIONS][CAP]
        const int* __restrict__ flags,
        const float4* __restrict__ x4,
        float4* __restrict__ agg4,
        const vfloat4* __restrict__ csrc,
        vfloat4* __restrict__ cdst) {
    int bid = blockIdx.x, tid = threadIdx.x;
    if (bid < K2_ALPHA_BLOCKS) {
        __shared__ float bsum;
        if (tid == 0) bsum = 0.f;
        __syncthreads();
        int wid  = bid * 4 + (tid >> 6);
        int lane = tid & 63;
        float4 w4 = make_float4(0.f, 0.f, 0.f, 0.f);
        if (lane < 50) w4 = ((const float4*)Watt)[lane];
        float bias = batt[0];
        int e0 = wid * ALPHA_CHUNK;
        int e1 = min(e0 + ALPHA_CHUNK, E_EDGES);
        float lsum = 0.f;
        for (int e = e0; e < e1; ++e) {
            int s = ei[e];
            int d = ei[E_EDGES + e];
            float acc = 0.f;
            if (lane < 50) {
                uint2 us = *(const uint2*)(P + (long)s * F_PROJ + lane * 4);
                uint2 ud = *(const uint2*)(P + (long)d * F_PROJ + lane * 4);
                acc = fabsf(bf16_to_f32((unsigned short)(ud.x & 0xFFFF)) -
                            bf16_to_f32((unsigned short)(us.x & 0xFFFF))) * w4.x
                    + fabsf(bf16_to_f32((unsigned short)(ud.x >> 16)) -
                            bf16_to_f32((unsigned short)(us.x >> 16))) * w4.y
                    + fabsf(bf16_to_f32((unsigned short)(ud.y & 0xFFFF)) -
                            bf16_to_f32((unsigned short)(us.y & 0xFFFF))) * w4.z
                    + fabsf(bf16_to_f32((unsigned short)(ud.y >> 16)) -
                            bf16_to_f32((unsigned short)(us.y >> 16))) * w4.w;
            }
            // xor-butterfly: ALL lanes end with the full sum
            #pragma unroll
            for (int off = 32; off; off >>= 1) acc += __shfl_xor(acc, off);
            float alpha = fmaxf(acc + bias, 0.f);
            float ea = expf(alpha);              // alpha in [0,~6]: safe
            // lane0 inserts cell (s,d) + accumulates sum; lane1 inserts (d,s):
            // both atomics issue in ONE wave instruction (parallel).
            if (lane < 2) {
                unsigned int li = (lane == 0)
                    ? (unsigned int)s * 10000u + (unsigned int)d
                    : (unsigned int)d * 10000u + (unsigned int)s;
                unsigned int r  = li / 20000u;
                unsigned int p  = li - r * 20000u;
                unsigned short h = __half_as_ushort(__float2half(ea));
                unsigned int idx = atomicAdd(&counts[r], 1u);
                if (idx < CAP) bucket[(long)r * CAP + idx] = (p << 16) | h;
                if (lane == 0) lsum += ea;
            }
        }
        if (lane == 0) atomicAdd(&bsum, lsum);
        __syncthreads();
        if (tid == 0) atomicAdd(sumbuf, bsum);
        return;
    }
    int b2 = bid - K2_ALPHA_BLOCKS;
    if (b2 < K2_COPY_REGS) {
        long r = K2_COPY_REG0 + b2;
        const vfloat4* s = csrc + r * REG_F4;
        vfloat4*       d = cdst + r * REG_F4;
        for (int i = tid; i < REG_F4; i += 256) {
            vfloat4 v = __builtin_nontemporal_load(s + i);
            __builtin_nontemporal_store(v, d + i);
        }
        return;
    }
    // agg role: flags ready since K1
    long base = (long)(b2 - K2_COPY_REGS) * AGG_PER_BLOCK;
    for (int i = tid; i < AGG_PER_BLOCK; i += 256) {
        long i4 = base + i;
        float4 v = x4[i4];
        if (!flags[i4 >> 6]) v = make_float4(0.f, 0.f, 0.f, 0.f);
        agg4[i4] = v;
    }
}

// ---- K3: copy+patch regions [900,5000) (4100) + patch-only [0,900) ----------
__global__ __launch_bounds__(256) void k3_copy_patch(
        const unsigned int* __restrict__ counts,
        const unsigned int* __restrict__ bucket,
        const float* __restrict__ sumbuf,
        const vfloat4* __restrict__ csrc,
        vfloat4* __restrict__ cdst,
        float* __restrict__ ev) {
    int bid = blockIdx.x, tid = threadIdx.x;
    int r;
    if (bid < K3_COPY_REGS) {
        r = K3_COPY_REG0 + bid;
        // normal cached copy (alpha done: pollution harmless; m13 peak pattern)
        const vfloat4* s = csrc + (long)r * REG_F4;
        vfloat4*       d = cdst + (long)r * REG_F4;
        for (int i = tid; i < REG_F4; i += 256) d[i] = s[i];
        __syncthreads();   // drains vmcnt: copy stores in L2 before patches
    } else {
        r = bid - K3_COPY_REGS;        // 0..899, copied in K1/K2 (kernel fence)
    }
    unsigned int cnt = counts[r];
    if (cnt > CAP) cnt = CAP;
    float inv = 1.0f / sumbuf[0];
    long base = (long)r * REG_FLOATS;
    for (unsigned int i = tid; i < cnt; i += 256) {
        unsigned int en = bucket[(long)r * CAP + i];
        float a = __half2float(__ushort_as_half((unsigned short)(en & 0xFFFFu))) * inv;
        ev[base + (en >> 16)] = a;     // patch wins: same-L2 ordering after sync
    }
}

// ================= FALLBACK PATH (round-5, proven) ===========================
#define N4_TOTAL 25000000L
#define S1_SPLIT 4000000L
#define FB1_PROJ_BLOCKS 1250
#define FB1_COPY_BLOCKS 768
#define FB2_BLOCKS 6144
#define FB2_ALPHA_BLOCKS 1536
#define FB2_COPY_BLOCKS (FB2_BLOCKS - FB2_ALPHA_BLOCKS)
#define FB2_ALPHA_WAVES (FB2_ALPHA_BLOCKS * 4)
#define FB_ALPHA_CHUNK ((E_EDGES + FB2_ALPHA_WAVES - 1) / FB2_ALPHA_WAVES)
#define FB_AGG_CHUNK ((AGG_N4 + FB2_ALPHA_BLOCKS - 1) / FB2_ALPHA_BLOCKS)

__global__ __launch_bounds__(256) void fb1_proj_flags_copy(
        const float* __restrict__ x, const float* __restrict__ W,
        unsigned short* __restrict__ P, const int* __restrict__ ei,
        int* __restrict__ flags,
        const vfloat4* __restrict__ csrc, vfloat4* __restrict__ cdst) {
    int bid = blockIdx.x, tid = threadIdx.x;
    if (bid >= FB1_PROJ_BLOCKS) {
        long i = (long)(bid - FB1_PROJ_BLOCKS) * 256 + tid;
        const long stride = (long)FB1_COPY_BLOCKS * 256;
        for (; i < S1_SPLIT; i += stride) {
            vfloat4 v = __builtin_nontemporal_load(csrc + i);
            __builtin_nontemporal_store(v, cdst + i);
        }
        return;
    }
    int gt = bid * 256 + tid;
    flags[ei[E_EDGES + gt]] = 1;
    __shared__ float xs[8][F_IN];
    int n0 = bid * 8;
    for (int i = tid; i < 8 * F_IN / 4; i += 256)
        ((float4*)xs)[i] = ((const float4*)(x + (long)n0 * F_IN))[i];
    __syncthreads();
    int j = tid;
    if (j >= F_PROJ) return;
    float acc[8] = {0.f,0.f,0.f,0.f,0.f,0.f,0.f,0.f};
    for (int k = 0; k < F_IN; ++k) {
        float w = W[k * F_PROJ + j];
        #pragma unroll
        for (int r = 0; r < 8; ++r) acc[r] += xs[r][k] * w;
    }
    #pragma unroll
    for (int r = 0; r < 8; ++r) P[(long)(n0 + r) * F_PROJ + j] = f32_to_bf16(acc[r]);
}

__global__ __launch_bounds__(256) void fb2_alpha_agg_copy(
        const int* __restrict__ ei, const unsigned short* __restrict__ P,
        const float* __restrict__ Watt, const float* __restrict__ batt,
        float* __restrict__ expalpha, float* __restrict__ sumbuf,
        const int* __restrict__ flags, const float4* __restrict__ x4,
        float4* __restrict__ agg4,
        const vfloat4* __restrict__ csrc, vfloat4* __restrict__ cdst) {
    int bid = blockIdx.x, tid = threadIdx.x;
    int role = bid & 3;
    if (role != 0) {
        long cid = (long)(bid >> 2) * 3 + (role - 1);
        long i = S1_SPLIT + cid * 256 + tid;
        const long stride = (long)FB2_COPY_BLOCKS * 256;
        for (; i < N4_TOTAL; i += stride) {
            vfloat4 v = __builtin_nontemporal_load(csrc + i);
            __builtin_nontemporal_store(v, cdst + i);
        }
        return;
    }
    __shared__ float bsum;
    if (tid == 0) bsum = 0.f;
    __syncthreads();
    int aid = bid >> 2, wid = aid * 4 + (tid >> 6), lane = tid & 63;
    float4 w4 = make_float4(0.f, 0.f, 0.f, 0.f);
    if (lane < 50) w4 = ((const float4*)Watt)[lane];
    float bias = batt[0];
    int e0 = wid * FB_ALPHA_CHUNK, e1 = min(e0 + FB_ALPHA_CHUNK, E_EDGES);
    float lsum = 0.f;
    for (int e = e0; e < e1; ++e) {
        int s = ei[e], d = ei[E_EDGES + e];
        float acc = 0.f;
        if (lane < 50) {
            uint2 us = *(const uint2*)(P + (long)s * F_PROJ + lane * 4);
            uint2 ud = *(const uint2*)(P + (long)d * F_PROJ + lane * 4);
            acc = fabsf(bf16_to_f32((unsigned short)(ud.x & 0xFFFF)) -
                        bf16_to_f32((unsigned short)(us.x & 0xFFFF))) * w4.x
                + fabsf(bf16_to_f32((unsigned short)(ud.x >> 16)) -
                        bf16_to_f32((unsigned short)(us.x >> 16))) * w4.y
                + fabsf(bf16_to_f32((unsigned short)(ud.y & 0xFFFF)) -
                        bf16_to_f32((unsigned short)(us.y & 0xFFFF))) * w4.z
                + fabsf(bf16_to_f32((unsigned short)(ud.y >> 16)) -
                        bf16_to_f32((unsigned short)(us.y >> 16))) * w4.w;
        }
        #pragma unroll
        for (int off = 32; off; off >>= 1) acc += __shfl_down(acc, off);
        if (lane == 0) {
            float ea = expf(fmaxf(acc + bias, 0.f));
            expalpha[e] = ea;
            lsum += ea;
        }
    }
    if (lane == 0) atomicAdd(&bsum, lsum);
    __syncthreads();
    if (tid == 0) atomicAdd(sumbuf, bsum);
    long a0 = (long)aid * FB_AGG_CHUNK;
    long a1 = a0 + FB_AGG_CHUNK; if (a1 > AGG_N4) a1 = AGG_N4;
    for (long i = a0 + tid; i < a1; i += 256) {
        float4 v = x4[i];
        if (!flags[i >> 6]) v = make_float4(0.f, 0.f, 0.f, 0.f);
        agg4[i] = v;
    }
}

__global__ __launch_bounds__(256) void fb3_scatter(
        const int* __restrict__ ei, const float* __restrict__ expalpha,
        const float* __restrict__ sumbuf, float* __restrict__ ev) {
    int e = blockIdx.x * 256 + threadIdx.x;
    if (e >= E_EDGES) return;
    float a = expalpha[e] / sumbuf[0];
    int s = ei[e], d = ei[E_EDGES + e];
    ev[(long)s * N_NODES + d] = a;
    ev[(long)d * N_NODES + s] = a;
}

// ================= host ======================================================
extern "C" void kernel_launch(void* const* d_in, const int* in_sizes, int n_in,
                              void* d_out, int out_size, void* d_ws, size_t ws_size,
                              hipStream_t stream) {
    (void)in_sizes; (void)n_in; (void)out_size;
    const float* x         = (const float*)d_in[0];
    const float* edge_attr = (const float*)d_in[1];
    const int*   ei        = (const int*)d_in[2];
    const float* W_proj    = (const float*)d_in[3];
    const float* W_att     = (const float*)d_in[5];
    const float* b_att     = (const float*)d_in[6];

    float* agg = (float*)d_out;
    float* ev  = (float*)d_out + (long)N_NODES * F_IN;
    char* ws = (char*)d_ws;

    if (ws_size >= (size_t)WS_NEED) {
        unsigned short* P   = (unsigned short*)(ws + WS_P);
        int*   flags        = (int*)(ws + WS_FLAGS);
        float* sumbuf       = (float*)(ws + WS_SUM);
        unsigned int* cnts  = (unsigned int*)(ws + WS_COUNTS);
        unsigned int* bkt   = (unsigned int*)(ws + WS_BUCKET);

        hipMemsetAsync(ws + WS_FLAGS, 0, WS_BUCKET - WS_FLAGS, stream);

        k1_proj_flags_copy<<<K1_PROJ_BLOCKS + K1_COPY_REGS, 256, 0, stream>>>(
            x, W_proj, P, ei, flags, (const vfloat4*)edge_attr, (vfloat4*)ev);

        k2_alpha_copy_agg<<<K2_ALPHA_BLOCKS + K2_COPY_REGS + K2_AGG_BLOCKS, 256, 0,
                            stream>>>(
            ei, P, W_att, b_att, sumbuf, cnts, bkt, flags,
            (const float4*)x, (float4*)agg,
            (const vfloat4*)edge_attr, (vfloat4*)ev);

        k3_copy_patch<<<NREGIONS, 256, 0, stream>>>(
            cnts, bkt, sumbuf, (const vfloat4*)edge_attr, (vfloat4*)ev, ev);
    } else {
        // proven round-5 fallback (fits in 5.33 MB of ws)
        unsigned short* P = (unsigned short*)(ws);
        float* expalpha   = (float*)(ws + 4000000);
        int*   flags      = (int*)(ws + 5280000);
        float* sumbuf     = (float*)(ws + 5320000);

        hipMemsetAsync(ws + 5280000, 0, 40016, stream);

        fb1_proj_flags_copy<<<FB1_PROJ_BLOCKS + FB1_COPY_BLOCKS, 256, 0, stream>>>(
            x, W_proj, P, ei, flags, (const vfloat4*)edge_attr, (vfloat4*)ev);

        fb2_alpha_agg_copy<<<FB2_BLOCKS, 256, 0, stream>>>(
            ei, P, W_att, b_att, expalpha, sumbuf, flags,
            (const float4*)x, (float4*)agg,
            (const vfloat4*)edge_attr, (vfloat4*)ev);

        fb3_scatter<<<(E_EDGES + 255) / 256, 256, 0, stream>>>(
            ei, expalpha, sumbuf, ev);
    }
}

// Round 7
// 271.954 us; speedup vs baseline: 1.1824x; 1.1824x over previous
//
#include <hip/hip_runtime.h>

#define N_NODES 10000
#define E_EDGES 320000
#define F_IN    256
#define F_PROJ  200

typedef float vfloat4 __attribute__((ext_vector_type(4)));

// ---------------- new-path geometry ------------------------------------------
#define A_BLOCKS    2048
#define A_WAVES     (A_BLOCKS * 4)                       // 8192
#define A_CHUNK     40                                   // 8192*40 >= 320000
#define AGG_BLOCKS  160
#define AGG_N4      (N_NODES * F_IN / 4)                 // 640000
#define AGG_PER_BLK (AGG_N4 / AGG_BLOCKS)                // 4000
#define EV_F4       25000000L                            // ev in float4s
#define BM_WORDS    3125000L                             // 1e8 cells / 32

// new-path workspace layout
#define WS_P      0L           // 4,000,000  (bf16 P)
#define WS_EXP    4000000L     // 1,280,000  (expalpha)
#define WS_FLAGS  5280000L     // 40,000
#define WS_SUM    5320000L     // 16
#define WS_BM     5320016L     // 12,500,000 (bitmap)
#define WS_NEED   (WS_BM + BM_WORDS * 4L)                // 17,820,016

__device__ __forceinline__ unsigned short f32_to_bf16(float f) {
    unsigned int u = __float_as_uint(f);
    u += 0x7FFFu + ((u >> 16) & 1u);
    return (unsigned short)(u >> 16);
}
__device__ __forceinline__ float bf16_to_f32(unsigned short b) {
    return __uint_as_float(((unsigned int)b) << 16);
}

// ================= NEW PATH ==================================================

// ---- K1: proj + flag-scan (1250 blocks; 320000 threads == E) ----------------
__global__ __launch_bounds__(256) void k1_proj_flags(
        const float* __restrict__ x,
        const float* __restrict__ W,
        unsigned short* __restrict__ P,
        const int* __restrict__ ei,
        int* __restrict__ flags) {
    int bid = blockIdx.x, tid = threadIdx.x;
    int gt = bid * 256 + tid;
    flags[ei[E_EDGES + gt]] = 1;                 // racy same-value store: fine

    __shared__ float xs[8][F_IN];
    int n0 = bid * 8;
    for (int i = tid; i < 8 * F_IN / 4; i += 256)
        ((float4*)xs)[i] = ((const float4*)(x + (long)n0 * F_IN))[i];
    __syncthreads();
    int j = tid;
    if (j >= F_PROJ) return;
    float acc[8] = {0.f,0.f,0.f,0.f,0.f,0.f,0.f,0.f};
    for (int k = 0; k < F_IN; ++k) {
        float w = W[k * F_PROJ + j];
        #pragma unroll
        for (int r = 0; r < 8; ++r) acc[r] += xs[r][k] * w;
    }
    #pragma unroll
    for (int r = 0; r < 8; ++r) P[(long)(n0 + r) * F_PROJ + j] = f32_to_bf16(acc[r]);
}

// ---- K2: alpha (2048 blocks) || agg (160 blocks) ----------------------------
__global__ __launch_bounds__(256) void k2_alpha_agg(
        const int* __restrict__ ei,
        const unsigned short* __restrict__ P,
        const float* __restrict__ Watt,
        const float* __restrict__ batt,
        float* __restrict__ expalpha,
        float* __restrict__ sumbuf,              // pre-zeroed
        const int* __restrict__ flags,           // from K1
        const float4* __restrict__ x4,
        float4* __restrict__ agg4) {
    int bid = blockIdx.x, tid = threadIdx.x;
    if (bid < A_BLOCKS) {
        __shared__ float bsum;
        if (tid == 0) bsum = 0.f;
        __syncthreads();
        int wid  = bid * 4 + (tid >> 6);
        int lane = tid & 63;
        float4 w4 = make_float4(0.f, 0.f, 0.f, 0.f);
        if (lane < 50) w4 = ((const float4*)Watt)[lane];
        float bias = batt[0];
        int e0 = wid * A_CHUNK;
        int e1 = min(e0 + A_CHUNK, E_EDGES);
        float lsum = 0.f;
        for (int e = e0; e < e1; ++e) {
            int s = ei[e];
            int d = ei[E_EDGES + e];
            float acc = 0.f;
            if (lane < 50) {
                uint2 us = *(const uint2*)(P + (long)s * F_PROJ + lane * 4);
                uint2 ud = *(const uint2*)(P + (long)d * F_PROJ + lane * 4);
                acc = fabsf(bf16_to_f32((unsigned short)(ud.x & 0xFFFF)) -
                            bf16_to_f32((unsigned short)(us.x & 0xFFFF))) * w4.x
                    + fabsf(bf16_to_f32((unsigned short)(ud.x >> 16)) -
                            bf16_to_f32((unsigned short)(us.x >> 16))) * w4.y
                    + fabsf(bf16_to_f32((unsigned short)(ud.y & 0xFFFF)) -
                            bf16_to_f32((unsigned short)(us.y & 0xFFFF))) * w4.z
                    + fabsf(bf16_to_f32((unsigned short)(ud.y >> 16)) -
                            bf16_to_f32((unsigned short)(us.y >> 16))) * w4.w;
            }
            #pragma unroll
            for (int off = 32; off; off >>= 1) acc += __shfl_down(acc, off);
            if (lane == 0) {
                float ea = expf(fmaxf(acc + bias, 0.f));   // alpha in [0,~6]
                expalpha[e] = ea;
                lsum += ea;
            }
        }
        if (lane == 0) atomicAdd(&bsum, lsum);
        __syncthreads();
        if (tid == 0) atomicAdd(sumbuf, bsum);
        return;
    }
    // agg role (flags ready since K1)
    long base = (long)(bid - A_BLOCKS) * AGG_PER_BLK;
    for (int i = tid; i < AGG_PER_BLK; i += 256) {
        long i4 = base + i;
        float4 v = x4[i4];
        if (!flags[i4 >> 6]) v = make_float4(0.f, 0.f, 0.f, 0.f);
        agg4[i4] = v;
    }
}

// ---- K3: scatter a into ev + set bitmap (BEFORE the copy) -------------------
// RMW lands in the memory-side LLC (lines stay warm for K4's merge reads).
__global__ __launch_bounds__(256) void k3_scatter_bm(
        const int* __restrict__ ei,
        const float* __restrict__ expalpha,
        const float* __restrict__ sumbuf,
        float* __restrict__ ev,
        unsigned int* __restrict__ bm) {         // pre-zeroed
    int e = blockIdx.x * 256 + threadIdx.x;
    if (e >= E_EDGES) return;
    float a = expalpha[e] / sumbuf[0];
    unsigned int s = (unsigned int)ei[e];
    unsigned int d = (unsigned int)ei[E_EDGES + e];
    unsigned int li1 = s * 10000u + d;
    unsigned int li2 = d * 10000u + s;
    ev[li1] = a;
    ev[li2] = a;
    atomicOr(&bm[li1 >> 5], 1u << (li1 & 31));
    atomicOr(&bm[li2 >> 5], 1u << (li2 & 31));
}

// ---- K4: merge-copy: ev = bitmap-bit ? ev(scattered a) : edge_attr ----------
// Pure stream (alpha done), nt on src/dst; bitmap + patched-line reads are
// cache hits. 97.4% of float4s take the fast path (nibble == 0).
__global__ __launch_bounds__(256) void k4_merge_copy(
        const vfloat4* __restrict__ src,
        vfloat4* __restrict__ dst,
        const unsigned int* __restrict__ bm) {
    long i = (long)blockIdx.x * 256 + threadIdx.x;
    const long stride = (long)gridDim.x * 256;
    for (; i < EV_F4; i += stride) {
        unsigned int w = bm[i >> 3];             // 8 consecutive lanes share
        vfloat4 v = __builtin_nontemporal_load(src + i);
        unsigned int nib = (w >> (((unsigned)i & 7u) * 4u)) & 0xFu;
        if (nib) {
            vfloat4 cur = dst[i];                // cached: LLC-warm from K3
            if (nib & 1u) v.x = cur.x;
            if (nib & 2u) v.y = cur.y;
            if (nib & 4u) v.z = cur.z;
            if (nib & 8u) v.w = cur.w;
        }
        __builtin_nontemporal_store(v, dst + i);
    }
}

// ================= FALLBACK PATH (round-5, proven 249 us) ====================
#define N4_TOTAL 25000000L
#define S1_SPLIT 4000000L
#define FB1_PROJ_BLOCKS 1250
#define FB1_COPY_BLOCKS 768
#define FB2_BLOCKS 6144
#define FB2_ALPHA_BLOCKS 1536
#define FB2_COPY_BLOCKS (FB2_BLOCKS - FB2_ALPHA_BLOCKS)
#define FB2_ALPHA_WAVES (FB2_ALPHA_BLOCKS * 4)
#define FB_ALPHA_CHUNK ((E_EDGES + FB2_ALPHA_WAVES - 1) / FB2_ALPHA_WAVES)
#define FB_AGG_CHUNK ((AGG_N4 + FB2_ALPHA_BLOCKS - 1) / FB2_ALPHA_BLOCKS)

__global__ __launch_bounds__(256) void fb1_proj_flags_copy(
        const float* __restrict__ x, const float* __restrict__ W,
        unsigned short* __restrict__ P, const int* __restrict__ ei,
        int* __restrict__ flags,
        const vfloat4* __restrict__ csrc, vfloat4* __restrict__ cdst) {
    int bid = blockIdx.x, tid = threadIdx.x;
    if (bid >= FB1_PROJ_BLOCKS) {
        long i = (long)(bid - FB1_PROJ_BLOCKS) * 256 + tid;
        const long stride = (long)FB1_COPY_BLOCKS * 256;
        for (; i < S1_SPLIT; i += stride) {
            vfloat4 v = __builtin_nontemporal_load(csrc + i);
            __builtin_nontemporal_store(v, cdst + i);
        }
        return;
    }
    int gt = bid * 256 + tid;
    flags[ei[E_EDGES + gt]] = 1;
    __shared__ float xs[8][F_IN];
    int n0 = bid * 8;
    for (int i = tid; i < 8 * F_IN / 4; i += 256)
        ((float4*)xs)[i] = ((const float4*)(x + (long)n0 * F_IN))[i];
    __syncthreads();
    int j = tid;
    if (j >= F_PROJ) return;
    float acc[8] = {0.f,0.f,0.f,0.f,0.f,0.f,0.f,0.f};
    for (int k = 0; k < F_IN; ++k) {
        float w = W[k * F_PROJ + j];
        #pragma unroll
        for (int r = 0; r < 8; ++r) acc[r] += xs[r][k] * w;
    }
    #pragma unroll
    for (int r = 0; r < 8; ++r) P[(long)(n0 + r) * F_PROJ + j] = f32_to_bf16(acc[r]);
}

__global__ __launch_bounds__(256) void fb2_alpha_agg_copy(
        const int* __restrict__ ei, const unsigned short* __restrict__ P,
        const float* __restrict__ Watt, const float* __restrict__ batt,
        float* __restrict__ expalpha, float* __restrict__ sumbuf,
        const int* __restrict__ flags, const float4* __restrict__ x4,
        float4* __restrict__ agg4,
        const vfloat4* __restrict__ csrc, vfloat4* __restrict__ cdst) {
    int bid = blockIdx.x, tid = threadIdx.x;
    int role = bid & 3;
    if (role != 0) {
        long cid = (long)(bid >> 2) * 3 + (role - 1);
        long i = S1_SPLIT + cid * 256 + tid;
        const long stride = (long)FB2_COPY_BLOCKS * 256;
        for (; i < N4_TOTAL; i += stride) {
            vfloat4 v = __builtin_nontemporal_load(csrc + i);
            __builtin_nontemporal_store(v, cdst + i);
        }
        return;
    }
    __shared__ float bsum;
    if (tid == 0) bsum = 0.f;
    __syncthreads();
    int aid = bid >> 2, wid = aid * 4 + (tid >> 6), lane = tid & 63;
    float4 w4 = make_float4(0.f, 0.f, 0.f, 0.f);
    if (lane < 50) w4 = ((const float4*)Watt)[lane];
    float bias = batt[0];
    int e0 = wid * FB_ALPHA_CHUNK, e1 = min(e0 + FB_ALPHA_CHUNK, E_EDGES);
    float lsum = 0.f;
    for (int e = e0; e < e1; ++e) {
        int s = ei[e], d = ei[E_EDGES + e];
        float acc = 0.f;
        if (lane < 50) {
            uint2 us = *(const uint2*)(P + (long)s * F_PROJ + lane * 4);
            uint2 ud = *(const uint2*)(P + (long)d * F_PROJ + lane * 4);
            acc = fabsf(bf16_to_f32((unsigned short)(ud.x & 0xFFFF)) -
                        bf16_to_f32((unsigned short)(us.x & 0xFFFF))) * w4.x
                + fabsf(bf16_to_f32((unsigned short)(ud.x >> 16)) -
                        bf16_to_f32((unsigned short)(us.x >> 16))) * w4.y
                + fabsf(bf16_to_f32((unsigned short)(ud.y & 0xFFFF)) -
                        bf16_to_f32((unsigned short)(us.y & 0xFFFF))) * w4.z
                + fabsf(bf16_to_f32((unsigned short)(ud.y >> 16)) -
                        bf16_to_f32((unsigned short)(us.y >> 16))) * w4.w;
        }
        #pragma unroll
        for (int off = 32; off; off >>= 1) acc += __shfl_down(acc, off);
        if (lane == 0) {
            float ea = expf(fmaxf(acc + bias, 0.f));
            expalpha[e] = ea;
            lsum += ea;
        }
    }
    if (lane == 0) atomicAdd(&bsum, lsum);
    __syncthreads();
    if (tid == 0) atomicAdd(sumbuf, bsum);
    long a0 = (long)aid * FB_AGG_CHUNK;
    long a1 = a0 + FB_AGG_CHUNK; if (a1 > AGG_N4) a1 = AGG_N4;
    for (long i = a0 + tid; i < a1; i += 256) {
        float4 v = x4[i];
        if (!flags[i >> 6]) v = make_float4(0.f, 0.f, 0.f, 0.f);
        agg4[i] = v;
    }
}

__global__ __launch_bounds__(256) void fb3_scatter(
        const int* __restrict__ ei, const float* __restrict__ expalpha,
        const float* __restrict__ sumbuf, float* __restrict__ ev) {
    int e = blockIdx.x * 256 + threadIdx.x;
    if (e >= E_EDGES) return;
    float a = expalpha[e] / sumbuf[0];
    int s = ei[e], d = ei[E_EDGES + e];
    ev[(long)s * N_NODES + d] = a;
    ev[(long)d * N_NODES + s] = a;
}

// ================= host ======================================================
extern "C" void kernel_launch(void* const* d_in, const int* in_sizes, int n_in,
                              void* d_out, int out_size, void* d_ws, size_t ws_size,
                              hipStream_t stream) {
    (void)in_sizes; (void)n_in; (void)out_size;
    const float* x         = (const float*)d_in[0];
    const float* edge_attr = (const float*)d_in[1];
    const int*   ei        = (const int*)d_in[2];
    const float* W_proj    = (const float*)d_in[3];
    const float* W_att     = (const float*)d_in[5];
    const float* b_att     = (const float*)d_in[6];

    float* agg = (float*)d_out;
    float* ev  = (float*)d_out + (long)N_NODES * F_IN;
    char* ws = (char*)d_ws;

    if (ws_size >= (size_t)WS_NEED) {
        unsigned short* P  = (unsigned short*)(ws + WS_P);
        float* expalpha    = (float*)(ws + WS_EXP);
        int*   flags       = (int*)(ws + WS_FLAGS);
        float* sumbuf      = (float*)(ws + WS_SUM);
        unsigned int* bm   = (unsigned int*)(ws + WS_BM);

        // zero flags + sum + bitmap (contiguous, one fill ~2us)
        hipMemsetAsync(ws + WS_FLAGS, 0, (WS_BM - WS_FLAGS) + BM_WORDS * 4L, stream);

        k1_proj_flags<<<FB1_PROJ_BLOCKS, 256, 0, stream>>>(
            x, W_proj, P, ei, flags);

        k2_alpha_agg<<<A_BLOCKS + AGG_BLOCKS, 256, 0, stream>>>(
            ei, P, W_att, b_att, expalpha, sumbuf, flags,
            (const float4*)x, (float4*)agg);

        k3_scatter_bm<<<(E_EDGES + 255) / 256, 256, 0, stream>>>(
            ei, expalpha, sumbuf, ev, bm);

        k4_merge_copy<<<8192, 256, 0, stream>>>(
            (const vfloat4*)edge_attr, (vfloat4*)ev, bm);
    } else {
        // proven round-5 fallback (fits in 5.33 MB of ws)
        unsigned short* P = (unsigned short*)(ws);
        float* expalpha   = (float*)(ws + 4000000);
        int*   flags      = (int*)(ws + 5280000);
        float* sumbuf     = (float*)(ws + 5320000);

        hipMemsetAsync(ws + 5280000, 0, 40016, stream);

        fb1_proj_flags_copy<<<FB1_PROJ_BLOCKS + FB1_COPY_BLOCKS, 256, 0, stream>>>(
            x, W_proj, P, ei, flags, (const vfloat4*)edge_attr, (vfloat4*)ev);

        fb2_alpha_agg_copy<<<FB2_BLOCKS, 256, 0, stream>>>(
            ei, P, W_att, b_att, expalpha, sumbuf, flags,
            (const float4*)x, (float4*)agg,
            (const vfloat4*)edge_attr, (vfloat4*)ev);

        fb3_scatter<<<(E_EDGES + 255) / 256, 256, 0, stream>>>(
            ei, expalpha, sumbuf, ev);
    }
}